// Round 1
// baseline (88.455 us; speedup 1.0000x reference)
//
#include <hip/hip_runtime.h>

#define B_      16
#define S_      65
#define R_      1040
#define W_      256
#define T_      2176
#define D_      128
#define MAXSEQ  2048

#define CHUNKS_ 32                    // W_/8 positions per row / 8 per block
#define NGATHER (R_ * CHUNKS_)        // 33280 gather blocks
#define NZERO   (B_ * MAXSEQ / 8)     // 4096 zero-fill blocks

// ---------------------------------------------------------------------------
// Kernel 1 (1 block, 256 thr): fully parallel setup.
//  - per-batch segment-offset scan: one wave per batch, __shfl_up scan
//  - per-row masked count (exact IEEE fp32 div predicate, matches jax ref)
//  - block-wide exclusive scan of counts (5 rows/thread)
//  - emits packed rowmeta[r] = {start, off, count, bits(scale+0.5)}
// ---------------------------------------------------------------------------
__global__ __launch_bounds__(256) void interp_setup(
    const float* __restrict__ scales,
    const int*   __restrict__ len_seq,
    const int*   __restrict__ len_seg_raw,
    int4* __restrict__ rowmeta,    // [R_] {start, off, count, sc_bits}
    int*  __restrict__ meta)       // [2] total, L
{
    __shared__ int s_len[R_];
    __shared__ int s_off[R_];
    __shared__ int s_wtot[4];
    const int tid  = threadIdx.x;
    const int lane = tid & 63;
    const int wid  = tid >> 6;

    for (int r = tid; r < R_; r += 256) s_len[r] = len_seg_raw[r] + 32; // +MIN_LEN_SEG
    __syncthreads();

    // per-batch exclusive cumsum of 65 segment lengths; one wave per batch
    for (int b = wid; b < B_; b += 4) {
        int v = s_len[b * S_ + lane];            // lanes 0..63 -> segs 0..63
        int incl = v;
        #pragma unroll
        for (int d = 1; d < 64; d <<= 1) {
            int n = __shfl_up(incl, d, 64);
            if (lane >= d) incl += n;
        }
        s_off[b * S_ + lane] = incl - v;         // exclusive prefix
        int tot = __shfl(incl, 63, 64);
        if (lane == 0) s_off[b * S_ + 64] = tot; // seg 64's exclusive prefix
    }
    __syncthreads();

    // per-row masked count: #{ w in [0,256) : fp32(w/sc) < K }
    int   c[5];
    int   offv[5];
    float scv[5];
    const int r0 = tid * 5;
    int tsum = 0;
    #pragma unroll
    for (int i = 0; i < 5; ++i) {
        int r = r0 + i, cc = 0, off = 0;
        float sc = 1.0f;
        if (r < R_) {
            sc  = scales[r] + 0.5f;
            off = s_off[r];
            int K = min(s_len[r] - 1, len_seq[r / S_] - 1 - off);
            if (K > 0) {
                cc = (int)ceilf((float)K * sc);
                cc = min(max(cc, 0), W_);
                const float Kf = (float)K;
                while (cc > 0  && ((float)(cc - 1) / sc) >= Kf) --cc; // exact IEEE div
                while (cc < W_ && ((float)cc       / sc) <  Kf) ++cc;
            }
        }
        c[i] = cc; offv[i] = off; scv[i] = sc; tsum += cc;
    }

    // block exclusive scan of per-thread sums
    int incl = tsum;
    #pragma unroll
    for (int d = 1; d < 64; d <<= 1) {
        int n = __shfl_up(incl, d, 64);
        if (lane >= d) incl += n;
    }
    if (lane == 63) s_wtot[wid] = incl;
    __syncthreads();
    int wpre = 0, total = 0;
    #pragma unroll
    for (int wv = 0; wv < 4; ++wv) {
        int t_ = s_wtot[wv];
        if (wv < wid) wpre += t_;
        total += t_;
    }
    int base = wpre + incl - tsum;               // exclusive prefix for this thread

    #pragma unroll
    for (int i = 0; i < 5; ++i) {
        int r = r0 + i;
        if (r < R_) {
            rowmeta[r] = make_int4(base, offv[i], c[i], __float_as_int(scv[i]));
            base += c[i];
        }
    }
    if (tid == 0) {
        meta[0] = total;
        meta[1] = total / B_;
    }
}

// ---------------------------------------------------------------------------
// Kernel 2: INPUT-driven gather + lerp. No LDS, no barrier, no binary search.
//  blocks [0, NGATHER):   (r, chunk) = (bid>>5, bid&31); 8 w-positions/block,
//                         32 lanes per position (float4 over D=128).
//                         p = start + w  ->  (b_out, t) = (p/L, p%L).
//  blocks [NGATHER, +NZERO): zero-fill output rows with t >= L.
//  The two ranges write disjoint output regions.
// ---------------------------------------------------------------------------
__global__ __launch_bounds__(256) void interp_gather(
    const float* __restrict__ x,
    const int4*  __restrict__ rowmeta,
    const int*   __restrict__ meta,
    float* __restrict__ out)
{
    const int tid  = threadIdx.x;
    const int sub  = tid >> 5;        // 0..7: position within block
    const int lane = tid & 31;        // float4 lane over D=128
    const int bid  = blockIdx.x;

    if (bid < NGATHER) {
        const int r     = bid >> 5;
        const int chunk = bid & (CHUNKS_ - 1);
        const int4 m    = rowmeta[r];              // broadcast 16B load
        const int count = m.z;
        const int wbase = chunk * 8;
        if (wbase >= count) return;                // empty chunk (most blocks)
        const int w = wbase + sub;
        if (w >= count) return;

        const int L = meta[1];
        const unsigned p  = (unsigned)(m.x + w);
        const unsigned BL = (unsigned)(B_ * L);
        if (p >= BL) return;                       // dropped tail (p >= B*L)
        const unsigned bo = p / (unsigned)L;       // output batch
        const int t = (int)(p - bo * (unsigned)L); // output timestep, t < L
        if (t >= MAXSEQ) return;                   // ref truncates at MAX_LEN_SEQ

        const float sc  = __int_as_float(m.w);
        const float is  = (float)w / sc;           // IEEE fp32 div, matches ref
        const float fl  = floorf(is);
        const float lam = is - fl;
        const int i0 = (int)fl + m.y;              // + per-row source offset
        const int bs = r / S_;                     // source batch (uniform/block)

        const float* base = x + (size_t)bs * (T_ * D_);
        const float4* pa = (const float4*)(base + (size_t)i0 * D_) + lane;
        const float4* pb = (const float4*)(base + (size_t)(i0 + 1) * D_) + lane;
        const float4 a = *pa, cc = *pb;
        const float om = 1.0f - lam;
        float4 y;
        y.x = om * a.x + lam * cc.x;
        y.y = om * a.y + lam * cc.y;
        y.z = om * a.z + lam * cc.z;
        y.w = om * a.w + lam * cc.w;
        float4* op = (float4*)(out + ((size_t)bo * MAXSEQ + t) * D_) + lane;
        *op = y;
    } else {
        const int L    = meta[1];
        const int orow = (bid - NGATHER) * 8 + sub;   // [0, 32768)
        const int t    = orow & (MAXSEQ - 1);
        if (t >= L) {                                  // tail rows only
            float4* op = (float4*)(out + (size_t)orow * D_) + lane;
            *op = make_float4(0.f, 0.f, 0.f, 0.f);
        }
    }
}

extern "C" void kernel_launch(void* const* d_in, const int* in_sizes, int n_in,
                              void* d_out, int out_size, void* d_ws, size_t ws_size,
                              hipStream_t stream) {
    const float* x           = (const float*)d_in[0];  // (16, 2176, 128) f32
    const float* scales      = (const float*)d_in[1];  // (1040,) f32
    const int*   len_seq     = (const int*)d_in[2];    // (16,) i32
    const int*   len_seg_raw = (const int*)d_in[3];    // (1040,1) i32
    float*       out         = (float*)d_out;          // (16, 2048, 128) f32

    int4* rowmeta = (int4*)d_ws;          // R_ x {start, off, count, sc_bits}
    int*  meta    = (int*)(rowmeta + R_); // [2] total, L

    interp_setup<<<1, 256, 0, stream>>>(scales, len_seq, len_seg_raw,
                                        rowmeta, meta);

    interp_gather<<<NGATHER + NZERO, 256, 0, stream>>>(x, rowmeta, meta, out);
}